// Round 8
// baseline (3051.342 us; speedup 1.0000x reference)
//
#include <hip/hip_runtime.h>
#include <stdint.h>
#include <stddef.h>

#define TT   128
#define BB   1024
#define INN  75
#define HH   128
#define KXP  96
#define OUTN 256
#define DECN 9600
#define EPSB 1e-5f
#define NRB  16          // row-blocks per mesh
#define RWS  64          // rows per block

typedef short v8s __attribute__((ext_vector_type(8)));   // 8 bf16 (4 VGPR) MFMA frag
typedef float v4f __attribute__((ext_vector_type(4)));   // 4 fp32 acc frag
typedef unsigned short ush;
typedef unsigned int   u32;
typedef unsigned long long u64;

#define MFMA(A,B,C) __builtin_amdgcn_mfma_f32_16x16x32_bf16((A),(B),(C),0,0,0)

// ---- static device workspace (fully rewritten every launch) ----
__device__ __align__(256) ush g_xpad[(size_t)TT * BB * KXP];   // x padded to K=96, [t][b][k] bf16
__device__ __align__(256) u64 g_G1[(size_t)TT * 32 * BB * 4];  // BN(x@Wih0)+b0, [t][g][row][16 bf16]
// weights [m][k] bf16, m permuted: origcol(m) = (m&3)*128 + (m>>4)*4 + ((m>>2)&3)
__device__ __align__(256) ush g_wtih0[512 * KXP];
__device__ __align__(256) ush g_wthh0[512 * HH];
__device__ __align__(256) ush g_wtih1[512 * HH];
__device__ __align__(256) ush g_wthh1[512 * HH];
__device__ __align__(256) ush g_fcwt[OUTN * HH];               // fc_w^T [col][k]
__device__ __align__(256) ush g_decwt[(size_t)DECN * OUTN];    // dec_w^T [col][k]
__device__ __align__(256) ush g_emb[BB * OUTN];                // fc output bf16
__device__ __align__(256) u64 g_hfin[BB * 32];                 // h1[TT-1], 4 bf16/u64 (for kfc)

// ---- tagged cross-block MAILBOX RINGS (slot = t&3). Working set ~12 MB ->
// MALL-resident after warm-up: no write-allocate HBM fills on the store path.
// Reuse safety: mesh flag rounds bound within-mesh skew to <=1 step; th0's
// unbounded producer (L0) is backpressured by g_l1p. Tag equality-poll makes
// stale slots (gen t-4 or prior launch) harmless. Relaxed agent atomics only.
// u64 formats: th0: [gen32 | 2 bf16]; gp/cp/soc: [tag16 | a:f24 | b:f24]
__device__ __align__(256) u64 g_th0[4][BB * 64];               // h0 ring [slot][row*64+j]
__device__ __align__(256) u64 g_gp[2][2][4][NRB * 512];        // [L][H][slot][rb*512 + col*2+st]
__device__ __align__(256) u64 g_cp[2][4][2][NRB * 64];         // [L][slot][H][rb*64 + ul]
__device__ __align__(256) u64 g_soc[2][4][2][BB * 64];         // [L][slot][H][row*64 + ul]
__device__ u32 g_l1p[2][NRB * 32];                             // L1 staging progress (H, rb)
__device__ u32 g_ep[64];                                       // per-block epoch (+=TT/launch)

// ---- helpers ----
__device__ __forceinline__ ush f2bf(float f) {
  u32 u = __float_as_uint(f);
  u32 r = (u + 0x7FFFu + ((u >> 16) & 1u)) >> 16;   // RNE
  return (ush)r;
}
__device__ __forceinline__ float bf2f(ush u) { return __uint_as_float(((u32)u) << 16); }
__device__ __forceinline__ float sigf(float x)  { return 1.f / (1.f + __expf(-x)); }
__device__ __forceinline__ float tanhf_(float x){ float e = __expf(2.f * x); return 1.f - 2.f / (e + 1.f); }
__device__ __forceinline__ v8s ld8(const ush* p) { return *reinterpret_cast<const v8s*>(p); }
__device__ __forceinline__ int origcol(int m) { return (m & 3) * 128 + (m >> 4) * 4 + ((m >> 2) & 3); }

__device__ __forceinline__ u64 ald(const u64* p) {
  return __hip_atomic_load(p, __ATOMIC_RELAXED, __HIP_MEMORY_SCOPE_AGENT);
}
__device__ __forceinline__ void ast(u64* p, u64 v) {
  __hip_atomic_store(p, v, __ATOMIC_RELAXED, __HIP_MEMORY_SCOPE_AGENT);
}
__device__ __forceinline__ u32 ald32(const u32* p) {
  return __hip_atomic_load(p, __ATOMIC_RELAXED, __HIP_MEMORY_SCOPE_AGENT);
}
__device__ __forceinline__ void ast32(u32* p, u32 v) {
  __hip_atomic_store(p, v, __ATOMIC_RELAXED, __HIP_MEMORY_SCOPE_AGENT);
}
__device__ __forceinline__ u64 pk24(u32 tag, float a, float b) {
  return ((u64)(tag & 0xFFFFu) << 48)
       | ((u64)(__float_as_uint(a) >> 8) << 24)
       | (u64)(__float_as_uint(b) >> 8);
}
__device__ __forceinline__ float upA24(u64 w) { return __uint_as_float(((u32)(w >> 24) & 0xFFFFFFu) << 8); }
__device__ __forceinline__ float upB24(u64 w) { return __uint_as_float(((u32)w & 0xFFFFFFu) << 8); }
__device__ __forceinline__ u32 tg16(u64 w) { return (u32)(w >> 48); }
// XOR-swizzled byte offset into a [64 rows][256 B] LDS h-tile
__device__ __forceinline__ int hswz(int r, int b) { return (r * 256 + b) ^ ((r & 7) << 4); }
__device__ __forceinline__ v8s ld8l(const char* lds, int r, int b) {
  return *reinterpret_cast<const v8s*>(lds + hswz(r, b));
}

// ---- prep kernels (unchanged, verified) ----
__global__ void kpackx(const float* __restrict__ seq) {
  int idx = blockIdx.x * 256 + threadIdx.x;   // < TT*BB*KXP
  int kk = idx % KXP; int rest = idx / KXP;
  int b = rest % BB;  int t = rest / BB;
  float v = (kk < INN) ? seq[((size_t)b * TT + t) * INN + kk] : 0.f;
  g_xpad[idx] = f2bf(v);
}

__global__ void kpackw(const float* __restrict__ Wih0, const float* __restrict__ Whh0,
                       const float* __restrict__ Wih1, const float* __restrict__ Whh1,
                       const float* __restrict__ fcw,  const float* __restrict__ decw) {
  int idx = blockIdx.x * 256 + threadIdx.x;   // grid 10688
  if (idx < 49152) {                          // wtih0: [m][96]
    int m = idx / KXP, k = idx % KXP;
    g_wtih0[idx] = f2bf((k < INN) ? Wih0[k * 512 + origcol(m)] : 0.f);
  } else if (idx < 114688) {
    int j = idx - 49152; int m = j / HH, k = j % HH;
    g_wthh0[j] = f2bf(Whh0[k * 512 + origcol(m)]);
  } else if (idx < 180224) {
    int j = idx - 114688; int m = j / HH, k = j % HH;
    g_wtih1[j] = f2bf(Wih1[k * 512 + origcol(m)]);
  } else if (idx < 245760) {
    int j = idx - 180224; int m = j / HH, k = j % HH;
    g_wthh1[j] = f2bf(Whh1[k * 512 + origcol(m)]);
  } else if (idx < 278528) {                  // fcwt [c][128]
    int j = idx - 245760; int c = j / HH, k = j % HH;
    g_fcwt[j] = f2bf(fcw[k * OUTN + c]);
  } else {                                    // decwt [c][256], coalesced reads
    int j = idx - 278528; int n = j % DECN, k = j / DECN;
    g_decwt[(size_t)n * OUTN + k] = f2bf(decw[(size_t)k * DECN + n]);
  }
}

// G1[t][g][row][16] = BN_ih0(x_t @ Wih0) + b0 (folded), transposed-MFMA orientation.
__global__ __launch_bounds__(512) void kprep(const float* __restrict__ gih0,
                                             const float* __restrict__ bih0,
                                             const float* __restrict__ b0) {
  const int t = blockIdx.x >> 3, ct = blockIdx.x & 7;
  const int tid = threadIdx.x, wv = tid >> 6, l = tid & 63;
  const int lm = l & 15, lq = l >> 4;
  const int R0 = wv * 128;
  __shared__ float sred[8][64][2];
  __shared__ float scoef[64][2];

  v8s af[4][3];
#pragma unroll
  for (int tt = 0; tt < 4; ++tt)
#pragma unroll
    for (int ks = 0; ks < 3; ++ks)
      af[tt][ks] = ld8(&g_wtih0[(ct * 64 + tt * 16 + lm) * KXP + ks * 32 + lq * 8]);

  const v4f vz = {0.f, 0.f, 0.f, 0.f};
  v4f acc[8][4];
#pragma unroll
  for (int mt = 0; mt < 8; ++mt)
#pragma unroll
    for (int tt = 0; tt < 4; ++tt) acc[mt][tt] = vz;

#pragma unroll
  for (int mt = 0; mt < 8; ++mt) {
    const ush* xr = g_xpad + ((size_t)t * BB + R0 + mt * 16 + lm) * KXP + lq * 8;
    v8s bx0 = ld8(xr), bx1 = ld8(xr + 32), bx2 = ld8(xr + 64);
#pragma unroll
    for (int tt = 0; tt < 4; ++tt) {
      acc[mt][tt] = MFMA(af[tt][0], bx0, acc[mt][tt]);
      acc[mt][tt] = MFMA(af[tt][1], bx1, acc[mt][tt]);
      acc[mt][tt] = MFMA(af[tt][2], bx2, acc[mt][tt]);
    }
  }
  float S[4][4], Q[4][4];
#pragma unroll
  for (int tt = 0; tt < 4; ++tt)
#pragma unroll
    for (int r = 0; r < 4; ++r) {
      float s = 0.f, q = 0.f;
#pragma unroll
      for (int mt = 0; mt < 8; ++mt) { float a = acc[mt][tt][r]; s += a; q += a * a; }
#pragma unroll
      for (int off = 1; off < 16; off <<= 1) { s += __shfl_xor(s, off); q += __shfl_xor(q, off); }
      S[tt][r] = s; Q[tt][r] = q;
    }
  if (lm == 0)
#pragma unroll
    for (int tt = 0; tt < 4; ++tt)
#pragma unroll
      for (int r = 0; r < 4; ++r) {
        sred[wv][tt * 16 + lq * 4 + r][0] = S[tt][r];
        sred[wv][tt * 16 + lq * 4 + r][1] = Q[tt][r];
      }
  __syncthreads();
  if (tid < 64) {
    float Sa = 0.f, Qa = 0.f;
#pragma unroll
    for (int w8 = 0; w8 < 8; ++w8) { Sa += sred[w8][tid][0]; Qa += sred[w8][tid][1]; }
    int oc = origcol(ct * 64 + tid);
    float m_ = Sa * (1.f / BB), v_ = Qa * (1.f / BB) - m_ * m_;
    float A = gih0[oc] * rsqrtf(v_ + EPSB);
    scoef[tid][0] = A; scoef[tid][1] = bih0[oc] - A * m_ + b0[oc];
  }
  __syncthreads();
  float CA[4][4], CD[4][4];
#pragma unroll
  for (int tt = 0; tt < 4; ++tt)
#pragma unroll
    for (int r = 0; r < 4; ++r) {
      CA[tt][r] = scoef[tt * 16 + lq * 4 + r][0];
      CD[tt][r] = scoef[tt * 16 + lq * 4 + r][1];
    }
#pragma unroll
  for (int mt = 0; mt < 8; ++mt) {
    const int row = R0 + mt * 16 + lm;
#pragma unroll
    for (int tt = 0; tt < 4; ++tt) {
      const int g = ct * 4 + tt;
      u32 lo = (u32)f2bf(CA[tt][0] * acc[mt][tt][0] + CD[tt][0])
             | ((u32)f2bf(CA[tt][1] * acc[mt][tt][1] + CD[tt][1]) << 16);
      u32 hi = (u32)f2bf(CA[tt][2] * acc[mt][tt][2] + CD[tt][2])
             | ((u32)f2bf(CA[tt][3] * acc[mt][tt][3] + CD[tt][3]) << 16);
      g_G1[(((size_t)t * 32 + g) * BB + row) * 4 + lq] = (u64)lo | ((u64)hi << 32);
    }
  }
}

// ---- krec8: R7 protocol on mod-4 MAILBOX RINGS (MALL-resident working set).
// 64 blocks x 512 thr. Block = (L=bid>>5, H=(bid>>4)&1, rb=bid&15):
// rows [rb*64,+64) x m-cols [H*256,+256). 2 tagged rounds/step (gate + c);
// (so,c) f24 exchange rebuilds sibling h locally (bit-identical both sides).
// L0 backpressured via g_l1p so th0 slot t&3 is never overwritten before both
// L1 readers staged gen t-4. All cross-block words [tag|payload] u64,
// relaxed agent atomics, zero fences.
__global__ __launch_bounds__(512, 1) void krec8(
    const float* __restrict__ ghh0, const float* __restrict__ bhh0,
    const float* __restrict__ gc0,  const float* __restrict__ bc0,
    const float* __restrict__ gih1, const float* __restrict__ bih1,
    const float* __restrict__ ghh1, const float* __restrict__ bhh1,
    const float* __restrict__ b1,   const float* __restrict__ gc1,
    const float* __restrict__ bc1) {
  const int bid = blockIdx.x;            // 0..63
  const int L = bid >> 5, H = (bid >> 4) & 1, rb = bid & 15;
  const int tid = threadIdx.x, w = tid >> 6, l = tid & 63;
  const int lm = l & 15, lq = l >> 4;
  const int R0 = rb * RWS;

  __shared__ u64 s_hA_[2048];            // L0: h0 recurrent tile; L1: staged h0[t]
  __shared__ u64 s_hB_[2048];            // L1: h1 recurrent tile
  __shared__ float s_gA[256], s_gB[256], s_bs[256];
  __shared__ float s_cgM[128], s_cbM[128];       // ALL 128 units of the layer
  __shared__ float s_cA[256], s_cB[256], s_cD[256], s_mual[2][256];
  __shared__ float s_ccA[128], s_ccD[128];
  __shared__ u32 s_base;
  char* const hA = reinterpret_cast<char*>(s_hA_);
  char* const hB = reinterpret_cast<char*>(s_hB_);

  if (tid == 0) s_base = ald32(&g_ep[bid]);
  if (tid < 256) {
    const int oc = origcol(H * 256 + tid);
    if (L == 0) { s_gA[tid] = ghh0[oc]; s_gB[tid] = 0.f; s_bs[tid] = bhh0[oc]; }
    else { s_gA[tid] = gih1[oc]; s_gB[tid] = ghh1[oc];
           s_bs[tid] = bih1[oc] + bhh1[oc] + b1[oc]; }
  }
  if (tid < 128) {
    s_cgM[tid] = (L ? gc1 : gc0)[tid];
    s_cbM[tid] = (L ? bc1 : bc0)[tid];
  }
  __syncthreads();
  const u32 base = s_base;

  // persistent weight fragments: wave w owns colTiles ct=0,1 -> cols H*256+(w*2+ct)*16..+15
  v8s afA[2][4], afB[2][4];
  {
    const ush* wA = L ? g_wtih1 : g_wthh0;
#pragma unroll
    for (int ct = 0; ct < 2; ++ct)
#pragma unroll
      for (int ks = 0; ks < 4; ++ks) {
        const int mrow = H * 256 + (w * 2 + ct) * 16 + lm;
        afA[ct][ks] = ld8(&wA[mrow * HH + ks * 32 + lq * 8]);
        if (L) afB[ct][ks] = ld8(&g_wthh1[mrow * HH + ks * 32 + lq * 8]);
      }
  }

  float creg[4][2] = {{0.f,0.f},{0.f,0.f},{0.f,0.f},{0.f,0.f}};
  const v4f vz = {0.f, 0.f, 0.f, 0.f};

#pragma unroll 1
  for (int t = 0; t < TT; ++t) {
    const u32 tagF = base + (u32)t + 1;
    const u32 t16 = tagF & 0xFFFFu;
    const int slot = t & 3;
    v4f PA[4][2], PB[4][2];
#pragma unroll
    for (int mt = 0; mt < 4; ++mt) {
      PA[mt][0] = vz; PA[mt][1] = vz; PB[mt][0] = vz; PB[mt][1] = vz;
    }
    u64 g1v[4][2];

    if (L == 0) {
      // G1 prefetch (plain cached loads; launch-constant data)
#pragma unroll
      for (int mt = 0; mt < 4; ++mt)
#pragma unroll
        for (int ct = 0; ct < 2; ++ct)
          g1v[mt][ct] = g_G1[(((size_t)t * 32 + H * 16 + w * 2 + ct) * BB
                              + R0 + mt * 16 + lm) * 4 + lq];
      // backpressure: don't overwrite th0 slot (gen t-4) before both L1
      // readers of rows rb staged it. Steady-state satisfied (L1 governs).
      if (t >= 3 && tid < 2) {
        while (ald32(&g_l1p[tid][rb * 32]) < base + (u32)t - 2)
          __builtin_amdgcn_s_sleep(1);
      }
    } else {
      // stage hA = h0[t] from ring (L0 runs ahead -> usually ready)
      const int row = tid >> 3, j0 = (tid & 7) * 8;
      const u64* p = &g_th0[slot][(R0 + row) * 64 + j0];
      u64 v[8];
#pragma unroll
      for (int k = 0; k < 8; ++k) v[k] = ald(p + k);
      for (;;) {
        bool ok = true;
#pragma unroll
        for (int k = 0; k < 8; ++k)
          if ((u32)(v[k] >> 32) != tagF) { v[k] = ald(p + k); ok = false; }
        if (ok) break;
        __builtin_amdgcn_s_sleep(1);
      }
#pragma unroll
      for (int k = 0; k < 8; ++k)
        *reinterpret_cast<u32*>(hA + hswz(row, (j0 + k) * 4)) = (u32)v[k];
    }
    __syncthreads();
    if (L == 1 && tid == 0) ast32(&g_l1p[H][rb * 32], tagF);   // staged gen t

    // ---- GEMMs from LDS (no polls on the recurrent path) ----
    if (L == 0) {
      if (t > 0) {
#pragma unroll
        for (int mt = 0; mt < 4; ++mt)
#pragma unroll
          for (int ks = 0; ks < 4; ++ks) {
            const v8s f = ld8l(hA, mt * 16 + lm, ks * 64 + lq * 16);
            PA[mt][0] = MFMA(afA[0][ks], f, PA[mt][0]);
            PA[mt][1] = MFMA(afA[1][ks], f, PA[mt][1]);
          }
      }
    } else {
#pragma unroll
      for (int mt = 0; mt < 4; ++mt)
#pragma unroll
        for (int ks = 0; ks < 4; ++ks) {
          const v8s f = ld8l(hA, mt * 16 + lm, ks * 64 + lq * 16);
          PA[mt][0] = MFMA(afA[0][ks], f, PA[mt][0]);
          PA[mt][1] = MFMA(afA[1][ks], f, PA[mt][1]);
        }
      if (t > 0) {
#pragma unroll
        for (int mt = 0; mt < 4; ++mt)
#pragma unroll
          for (int ks = 0; ks < 4; ++ks) {
            const v8s f = ld8l(hB, mt * 16 + lm, ks * 64 + lq * 16);
            PB[mt][0] = MFMA(afB[0][ks], f, PB[mt][0]);
            PB[mt][1] = MFMA(afB[1][ks], f, PB[mt][1]);
          }
      }
    }

    // ---- gate stats over own 64 rows -> packed tagged publish ----
    u64* const gpO = &g_gp[L][H][slot][rb * 512];
#pragma unroll
    for (int ct = 0; ct < 2; ++ct) {
      float sA[4], qA[4], sB[4], qB[4];
#pragma unroll
      for (int r = 0; r < 4; ++r) {
        float s1 = PA[0][ct][r] + PA[1][ct][r] + PA[2][ct][r] + PA[3][ct][r];
        float q1 = PA[0][ct][r]*PA[0][ct][r] + PA[1][ct][r]*PA[1][ct][r]
                 + PA[2][ct][r]*PA[2][ct][r] + PA[3][ct][r]*PA[3][ct][r];
        float s2 = PB[0][ct][r] + PB[1][ct][r] + PB[2][ct][r] + PB[3][ct][r];
        float q2 = PB[0][ct][r]*PB[0][ct][r] + PB[1][ct][r]*PB[1][ct][r]
                 + PB[2][ct][r]*PB[2][ct][r] + PB[3][ct][r]*PB[3][ct][r];
#pragma unroll
        for (int off = 1; off < 16; off <<= 1) {
          s1 += __shfl_xor(s1, off); q1 += __shfl_xor(q1, off);
          if (L) { s2 += __shfl_xor(s2, off); q2 += __shfl_xor(q2, off); }
        }
        sA[r] = s1; qA[r] = q1; sB[r] = s2; qB[r] = q2;
      }
      if (lm == 0) {
        const int m0 = (w * 2 + ct) * 16 + lq * 4;
#pragma unroll
        for (int r = 0; r < 4; ++r) {
          ast(&gpO[(m0 + r) * 2], pk24(tagF, sA[r], qA[r]));
          if (L) ast(&gpO[(m0 + r) * 2 + 1], pk24(tagF, sB[r], qB[r]));
        }
      }
    }
    __syncthreads();

    // ---- ROUND 1: gate all-to-all poll + coefs ----
    {
      const int st = tid >> 8, m = tid & 255;
      if (st == 0 || L == 1) {
        const u64* pb = &g_gp[L][H][slot][0] + m * 2 + st;
        u64 v[16];
#pragma unroll
        for (int r2 = 0; r2 < 16; ++r2) v[r2] = ald(pb + (size_t)r2 * 512);
        for (;;) {
          bool ok = true;
#pragma unroll
          for (int r2 = 0; r2 < 16; ++r2)
            if (tg16(v[r2]) != t16) { v[r2] = ald(pb + (size_t)r2 * 512); ok = false; }
          if (ok) break;
          __builtin_amdgcn_s_sleep(1);
        }
        float S = 0.f, Q = 0.f;
#pragma unroll
        for (int r2 = 0; r2 < 16; ++r2) { S += upA24(v[r2]); Q += upB24(v[r2]); }
        const float mu = S * (1.f / BB), var = Q * (1.f / BB) - mu * mu;
        const float A = (st ? s_gB[m] : s_gA[m]) * rsqrtf(var + EPSB);
        if (st == 0) s_cA[m] = A; else s_cB[m] = A;
        s_mual[st][m] = A * mu;
      }
    }
    __syncthreads();
    if (tid < 256) s_cD[tid] = s_bs[tid] - s_mual[0][tid] - (L ? s_mual[1][tid] : 0.f);
    __syncthreads();

    // ---- pointwise + c update; publish (so,c) f24 AND c-partials together ----
    u64* const cpO = &g_cp[L][slot][H][rb * 64];
    u64* const socO = &g_soc[L][slot][H][0];
    float soq[4][2], cq_[4][2];
#pragma unroll
    for (int ct = 0; ct < 2; ++ct) {
      const int mb = (w * 2 + ct) * 16 + lq * 4;
      const v4f cA = *reinterpret_cast<const v4f*>(&s_cA[mb]);
      const v4f cD = *reinterpret_cast<const v4f*>(&s_cD[mb]);
      const v4f cB = *reinterpret_cast<const v4f*>(&s_cB[mb]);
      const int ul = (w * 2 + ct) * 4 + lq;
      float cs = 0.f, cqs = 0.f;
#pragma unroll
      for (int mt = 0; mt < 4; ++mt) {
        float gv[4];
        if (L == 0) {
          const u64 g1 = g1v[mt][ct];
          gv[0] = bf2f((ush)g1)         + cA[0] * PA[mt][ct][0] + cD[0];
          gv[1] = bf2f((ush)(g1 >> 16)) + cA[1] * PA[mt][ct][1] + cD[1];
          gv[2] = bf2f((ush)(g1 >> 32)) + cA[2] * PA[mt][ct][2] + cD[2];
          gv[3] = bf2f((ush)(g1 >> 48)) + cA[3] * PA[mt][ct][3] + cD[3];
        } else {
#pragma unroll
          for (int r = 0; r < 4; ++r)
            gv[r] = cA[r] * PA[mt][ct][r] + cB[r] * PB[mt][ct][r] + cD[r];
        }
        const float cold = (t == 0) ? 0.f : creg[mt][ct];
        const float c1 = sigf(gv[0]) * cold + sigf(gv[1]) * tanhf_(gv[3]);
        creg[mt][ct] = c1;
        const float so = sigf(gv[2]);
        const u64 ws = pk24(tagF, so, c1);
        ast(&socO[(size_t)(R0 + mt * 16 + lm) * 64 + ul], ws);
        const float soQ = upA24(ws), cQ = upB24(ws);   // quantized copies (bit-shared w/ sibling)
        soq[mt][ct] = soQ; cq_[mt][ct] = cQ;
        cs += cQ; cqs += cQ * cQ;
      }
#pragma unroll
      for (int off = 1; off < 16; off <<= 1) { cs += __shfl_xor(cs, off); cqs += __shfl_xor(cqs, off); }
      if (lm == 0) ast(&cpO[ul], pk24(tagF, cs, cqs));
    }
    __syncthreads();

    // ---- ROUND 2: c-partials (tid<128, unit tid, 16 sources) + sibling (so,c) ----
    u64 sv[8];
    if (tid < 128) {
      const int Hs = tid >> 6, us = tid & 63;
      const u64* pc = &g_cp[L][slot][Hs][us];
      u64 v[16];
#pragma unroll
      for (int r2 = 0; r2 < 16; ++r2) v[r2] = ald(pc + (size_t)r2 * 64);
      for (;;) {
        bool ok = true;
#pragma unroll
        for (int r2 = 0; r2 < 16; ++r2)
          if (tg16(v[r2]) != t16) { v[r2] = ald(pc + (size_t)r2 * 64); ok = false; }
        if (ok) break;
        __builtin_amdgcn_s_sleep(1);
      }
      float S = 0.f, Q = 0.f;
#pragma unroll
      for (int r2 = 0; r2 < 16; ++r2) { S += upA24(v[r2]); Q += upB24(v[r2]); }
      const float mu = S * (1.f / BB), var = Q * (1.f / BB) - mu * mu;
      const float ac = s_cgM[tid] * rsqrtf(var + EPSB);
      s_ccA[tid] = ac; s_ccD[tid] = s_cbM[tid] - ac * mu;
    }
    {
      const int rloc = tid >> 3, u0 = (tid & 7) * 8;
      const u64* ps = &g_soc[L][slot][1 - H][(size_t)(R0 + rloc) * 64 + u0];
#pragma unroll
      for (int k = 0; k < 8; ++k) sv[k] = ald(ps + k);
      for (;;) {
        bool ok = true;
#pragma unroll
        for (int k = 0; k < 8; ++k)
          if (tg16(sv[k]) != t16) { sv[k] = ald(ps + k); ok = false; }
        if (ok) break;
        __builtin_amdgcn_s_sleep(1);
      }
    }
    __syncthreads();

    // ---- h: own half (regs) + sibling half (from sv) -> LDS; L0 publishes th0 ----
    char* const town = L ? hB : hA;
#pragma unroll
    for (int ct = 0; ct < 2; ++ct) {
      const int ul = (w * 2 + ct) * 4 + lq;
      const int ug = H * 64 + ul;
      const float ac = s_ccA[ug], dc = s_ccD[ug];
#pragma unroll
      for (int mt = 0; mt < 4; ++mt) {
        const int rowl = mt * 16 + lm;
        const u32 v = (u32)f2bf(soq[mt][ct] * tanhf_(ac * cq_[mt][ct] + dc));
        const u32 a = v | (__shfl_xor(v, 16) << 16);   // valid on even lq
        if (lq == 0 || lq == 2) {
          const int jg = H * 32 + (w * 2 + ct) * 2 + (lq >> 1);
          *reinterpret_cast<u32*>(town + hswz(rowl, jg * 4)) = a;
          if (L == 0)
            ast(&g_th0[slot][(R0 + rowl) * 64 + jg], (((u64)tagF) << 32) | a);
        }
        if (L == 1 && t == TT - 1) {
          const u32 b2 = __shfl_xor(a, 32);
          if (lq == 0)
            g_hfin[(size_t)(R0 + rowl) * 32 + H * 16 + (w * 2 + ct)] = (u64)a | ((u64)b2 << 32);
        }
      }
    }
    {
      const int rloc = tid >> 3, u0 = (tid & 7) * 8;
#pragma unroll
      for (int k = 0; k < 8; ++k) {
        const int ugs = (1 - H) * 64 + u0 + k;
        const float hs = upA24(sv[k]) * tanhf_(s_ccA[ugs] * upB24(sv[k]) + s_ccD[ugs]);
        *reinterpret_cast<ush*>(town + hswz(rloc, ugs * 2)) = f2bf(hs);
      }
    }
    __syncthreads();   // tiles complete + publishes issued before next step
  }

  if (tid == 0) ast32(&g_ep[bid], base + TT);
}

// ---- epilogue: emb = h1(T-1) @ fc_w + fc_b (bf16 out) ----
__global__ __launch_bounds__(256) void kfc(const float* __restrict__ fcb) {
  const int tid = threadIdx.x, w = tid >> 6, l = tid & 63;
  const int lm = l & 15, lq = l >> 4;
  const int col = blockIdx.x * 16 + lm;   // grid 16
  const ush* hsrc = reinterpret_cast<const ush*>(g_hfin);
  v8s bf[4];
#pragma unroll
  for (int ks = 0; ks < 4; ++ks) bf[ks] = ld8(&g_fcwt[col * HH + ks * 32 + lq * 8]);
  const float bias = fcb[col];
  const v4f vz = {0.f, 0.f, 0.f, 0.f};
#pragma unroll
  for (int mt = 0; mt < 16; ++mt) {
    const int rowa = w * 256 + mt * 16 + lm;
    const ush* ap = hsrc + (size_t)rowa * HH + lq * 8;
    v4f acc = vz;
#pragma unroll
    for (int ks = 0; ks < 4; ++ks)
      acc = MFMA(ld8(ap + ks * 32), bf[ks], acc);
#pragma unroll
    for (int r = 0; r < 4; ++r) {
      int row = w * 256 + mt * 16 + lq * 4 + r;
      g_emb[row * OUTN + col] = f2bf(acc[r] + bias);
    }
  }
}

// ---- epilogue: out = emb @ dec_w + dec_b, transposed MFMA -> 16B coalesced stores ----
__global__ __launch_bounds__(256) void kdec(const float* __restrict__ decb, float* __restrict__ out) {
  const int tid = threadIdx.x, wv = tid >> 6, l = tid & 63;
  const int lm = l & 15, lq = l >> 4;
  const int c0 = blockIdx.x * 16;         // grid 600
  const int R0 = wv * 256;
  v8s af[8];
#pragma unroll
  for (int ks = 0; ks < 8; ++ks) af[ks] = ld8(&g_decwt[(size_t)(c0 + lm) * OUTN + ks * 32 + lq * 8]);
  float bias[4];
#pragma unroll
  for (int r = 0; r < 4; ++r) bias[r] = decb[c0 + lq * 4 + r];
  const v4f vz = {0.f, 0.f, 0.f, 0.f};
#pragma unroll
  for (int mt = 0; mt < 16; ++mt) {
    const int row = R0 + mt * 16 + lm;
    const ush* bp = g_emb + (size_t)row * OUTN + lq * 8;
    v4f acc = vz;
#pragma unroll
    for (int ks = 0; ks < 8; ++ks)
      acc = MFMA(af[ks], ld8(bp + ks * 32), acc);
    v4f o;
#pragma unroll
    for (int r = 0; r < 4; ++r) o[r] = acc[r] + bias[r];
    *reinterpret_cast<v4f*>(&out[(size_t)row * DECN + c0 + lq * 4]) = o;
  }
}

extern "C" void kernel_launch(void* const* d_in, const int* in_sizes, int n_in,
                              void* d_out, int out_size, void* d_ws, size_t ws_size,
                              hipStream_t stream) {
  const float* seq  = (const float*)d_in[0];
  const float* Wih0 = (const float*)d_in[1];
  const float* Whh0 = (const float*)d_in[2];
  const float* b0   = (const float*)d_in[3];
  const float* gih0 = (const float*)d_in[4];
  const float* bih0 = (const float*)d_in[5];
  const float* ghh0 = (const float*)d_in[6];
  const float* bhh0 = (const float*)d_in[7];
  const float* gc0  = (const float*)d_in[8];
  const float* bc0  = (const float*)d_in[9];
  const float* Wih1 = (const float*)d_in[10];
  const float* Whh1 = (const float*)d_in[11];
  const float* b1   = (const float*)d_in[12];
  const float* gih1 = (const float*)d_in[13];
  const float* bih1 = (const float*)d_in[14];
  const float* ghh1 = (const float*)d_in[15];
  const float* bhh1 = (const float*)d_in[16];
  const float* gc1  = (const float*)d_in[17];
  const float* bc1  = (const float*)d_in[18];
  const float* fcw  = (const float*)d_in[19];
  const float* fcb  = (const float*)d_in[20];
  const float* decw = (const float*)d_in[21];
  const float* decb = (const float*)d_in[22];
  float* out = (float*)d_out;
  (void)in_sizes; (void)n_in; (void)out_size; (void)d_ws; (void)ws_size;

  kpackx<<<dim3((TT * BB * KXP) / 256), dim3(256), 0, stream>>>(seq);
  kpackw<<<dim3(10688), dim3(256), 0, stream>>>(Wih0, Whh0, Wih1, Whh1, fcw, decw);
  kprep<<<dim3(TT * 8), dim3(512), 0, stream>>>(gih0, bih0, b0);
  krec8<<<dim3(64), dim3(512), 0, stream>>>(ghh0, bhh0, gc0, bc0,
                                            gih1, bih1, ghh1, bhh1, b1, gc1, bc1);
  kfc<<<dim3(16), dim3(256), 0, stream>>>(fcb);
  kdec<<<dim3(600), dim3(256), 0, stream>>>(decb, out);
}